// Round 8
// baseline (111.583 us; speedup 1.0000x reference)
//
#include <hip/hip_runtime.h>

#define IN   128
#define HID  16
#define OUT  64
#define BK   64        // nodes per bucket (bucket = dst >> 6)
#define EPB  16384     // edges per partition block
#define CAP  2048      // LDS staging capacity per bucket (mean ~1024)
#define PB   64        // nodes per proj block

// ---- K1 (fused): proj blocks [0,nproj) compute xs/xn with weights in VGPRs;
//      remaining B blocks do the per-block bucket histogram (R5-proven fusion).
__global__ void __launch_bounds__(256)
k_proj_part1(const float* __restrict__ x,
             const float* __restrict__ Ws,
             const float* __restrict__ Wn,
             const int* __restrict__ dst,
             float* __restrict__ xs,
             float* __restrict__ xn,
             int* __restrict__ histT,
             int n, int e, int nproj, int K, int B) {
    __shared__ float smem[12288];   // 48 KB, role-overlaid
    int tid = threadIdx.x;          // 256
    if ((int)blockIdx.x < nproj) {
        float (*lw)[32] = (float (*)[32])smem;          // 16 KB [128][32]
        float (*lx)[IN] = (float (*)[IN])(smem + 4096); // 32 KB [64][128]
        // stage combined weights [k][j]: j<16 -> Ws, else Wn
        for (int i = tid; i < IN * 32; i += 256) {
            int k = i >> 5, j = i & 31;
            lw[k][j] = (j < HID) ? Ws[k * HID + j] : Wn[k * HID + (j - 16)];
        }
        // stage 64 node rows as float4 (coalesced)
        int node0 = blockIdx.x * PB;
        const float4* x4 = (const float4*)x;
        float4* lx4 = (float4*)lx;
        for (int i = tid; i < PB * 32; i += 256) {
            int row = i >> 5, c4 = i & 31;
            int node = node0 + row;
            lx4[i] = (node < n) ? x4[(size_t)node * 32 + c4]
                                : make_float4(0.f, 0.f, 0.f, 0.f);
        }
        __syncthreads();
        // lane -> (j, k-half); fill 64 weight regs via one-time LDS reads
        int lane = tid & 63;
        int wave = tid >> 6;
        int j  = lane & 31;
        int kh = lane >> 5;          // 0: k in [0,64), 1: k in [64,128)
        float wv[64];
        #pragma unroll
        for (int m = 0; m < 64; ++m) wv[m] = lw[kh * 64 + m][j];
        // each wave owns 16 rows; per row: 16 b128 broadcast reads + 64 FMA
        #pragma unroll 1
        for (int rr = 0; rr < 16; ++rr) {
            int r = wave * 16 + rr;
            const float4* lxr = (const float4*)lx[r];
            float a = 0.f;
            #pragma unroll
            for (int m4 = 0; m4 < 16; ++m4) {
                float4 xv = lxr[kh * 16 + m4];
                a += xv.x * wv[m4 * 4 + 0];
                a += xv.y * wv[m4 * 4 + 1];
                a += xv.z * wv[m4 * 4 + 2];
                a += xv.w * wv[m4 * 4 + 3];
            }
            a += __shfl_xor(a, 32);   // combine the two k-halves
            int node = node0 + r;
            if (lane < 32 && node < n) {
                if (j < HID) xs[(size_t)node * HID + j] = a;
                else         xn[(size_t)node * HID + (j - 16)] = a;
            }
        }
    } else {
        int* lh = (int*)smem;               // K <= 1024 counters
        int blk = blockIdx.x - nproj;
        for (int i = tid; i < K; i += 256) lh[i] = 0;
        __syncthreads();
        const int4* d4 = (const int4*)dst;
        #pragma unroll
        for (int it = 0; it < EPB / 1024; ++it) {   // 16 iters x 256 thr x 4
            int i4 = blk * (EPB / 4) + it * 256 + tid;
            int elem = i4 * 4;
            if (elem + 3 < e) {
                int4 v = d4[i4];
                atomicAdd(&lh[v.x >> 6], 1);
                atomicAdd(&lh[v.y >> 6], 1);
                atomicAdd(&lh[v.z >> 6], 1);
                atomicAdd(&lh[v.w >> 6], 1);
            } else {
                for (int jj = elem; jj < e && jj < elem + 4; ++jj)
                    atomicAdd(&lh[dst[jj] >> 6], 1);
            }
        }
        __syncthreads();
        for (int b = tid; b < K; b += 256) histT[b * B + blk] = lh[b];
    }
}

// ---- K2: fused bucket totals + exclusive scan (single block)
__global__ void __launch_bounds__(1024)
k_scanAB(const int* __restrict__ histT, int* __restrict__ boff,
         int K, int B, int e) {
    __shared__ int sm[1024];
    int tid = threadIdx.x;
    int s = 0;
    if (tid < K) {
        const int* row = histT + (size_t)tid * B;
        for (int i = 0; i < B; ++i) s += row[i];
    }
    sm[tid] = s;
    __syncthreads();
    for (int off = 1; off < 1024; off <<= 1) {
        int t = (tid >= off) ? sm[tid - off] : 0;
        __syncthreads();
        sm[tid] += t;
        __syncthreads();
    }
    if (tid < K) boff[tid] = sm[tid] - s;
    if (tid == 0) boff[K] = e;
}

// ---- K3: scatter; per-(bucket,block) base computed inline from raw histT.
__global__ void __launch_bounds__(1024)
k_part2(const int* __restrict__ src, const int* __restrict__ dst,
        const int* __restrict__ histT, const int* __restrict__ boff,
        unsigned* __restrict__ bedge, int e, int K, int B) {
    __shared__ int lbase[1024];
    int tid = threadIdx.x, blk = blockIdx.x;
    for (int b = tid; b < K; b += 1024) {
        const int* row = histT + (size_t)b * B;
        int s = boff[b];
        for (int i = 0; i < blk; ++i) s += row[i];
        lbase[b] = s;
    }
    __syncthreads();
    const int4* s4 = (const int4*)src;
    const int4* d4 = (const int4*)dst;
    #pragma unroll
    for (int it = 0; it < EPB / 4096; ++it) {
        int i4 = blk * (EPB / 4) + it * 1024 + tid;
        int elem = i4 * 4;
        if (elem + 3 < e) {
            int4 sv = s4[i4];
            int4 dv = d4[i4];
            int p0 = atomicAdd(&lbase[dv.x >> 6], 1);
            int p1 = atomicAdd(&lbase[dv.y >> 6], 1);
            int p2 = atomicAdd(&lbase[dv.z >> 6], 1);
            int p3 = atomicAdd(&lbase[dv.w >> 6], 1);
            bedge[p0] = ((unsigned)sv.x << 6) | (unsigned)(dv.x & 63);
            bedge[p1] = ((unsigned)sv.y << 6) | (unsigned)(dv.y & 63);
            bedge[p2] = ((unsigned)sv.z << 6) | (unsigned)(dv.z & 63);
            bedge[p3] = ((unsigned)sv.w << 6) | (unsigned)(dv.w & 63);
        } else {
            for (int j = elem; j < e && j < elem + 4; ++j) {
                int pos = atomicAdd(&lbase[dst[j] >> 6], 1);
                bedge[pos] = ((unsigned)src[j] << 6) | (unsigned)(dst[j] & 63);
            }
        }
    }
}

// ---- K4: per-bucket fine segmentation + register pull + relu finish.
//      Also emits fine CSR (fsrc, rowptr) for K5.
__global__ void __launch_bounds__(512)
k_agg1(const unsigned* __restrict__ bedge, const int* __restrict__ boff,
       const float* __restrict__ xs, const float* __restrict__ xn,
       const float* __restrict__ b1, float* __restrict__ h,
       int* __restrict__ fsrc, int* __restrict__ rowptr, int n, int K) {
    __shared__ int ltmp[CAP];
    __shared__ int lsrc[CAP];
    __shared__ int lcnt[BK];
    __shared__ int lofs[BK + 1];
    __shared__ int lcur[BK];
    int tid = threadIdx.x, b = blockIdx.x;
    int s0 = boff[b], s1 = boff[b + 1], cnt = s1 - s0;
    bool fits = (cnt <= CAP);
    if (tid < BK) lcnt[tid] = 0;
    __syncthreads();
    if (fits) {
        for (int i = tid; i < cnt; i += 512) {
            int p = (int)bedge[s0 + i];
            ltmp[i] = p;
            atomicAdd(&lcnt[p & 63], 1);
        }
    } else {
        for (int i = tid; i < cnt; i += 512)
            atomicAdd(&lcnt[(int)bedge[s0 + i] & 63], 1);
    }
    __syncthreads();
    if (tid < BK) {               // wave-level inclusive shfl scan of 64 counts
        int v = lcnt[tid];
        #pragma unroll
        for (int off = 1; off < 64; off <<= 1) {
            int t = __shfl_up(v, off);
            if (tid >= off) v += t;
        }
        lofs[tid + 1] = v;
        if (tid == 0) lofs[0] = 0;
        lcur[tid] = lofs[tid];
    }
    __syncthreads();
    if (fits) {
        for (int i = tid; i < cnt; i += 512) {
            int p = ltmp[i];
            int r = atomicAdd(&lcur[p & 63], 1);
            lsrc[r] = p >> 6;
        }
    } else {
        for (int i = tid; i < cnt; i += 512) {
            int p = (int)bedge[s0 + i];
            int r = atomicAdd(&lcur[p & 63], 1);
            fsrc[s0 + r] = p >> 6;
        }
        __threadfence_block();
    }
    __syncthreads();
    if (fits)
        for (int i = tid; i < cnt; i += 512) fsrc[s0 + i] = lsrc[i];
    int node0 = b * BK;
    if (tid < BK) rowptr[node0 + tid] = s0 + lofs[tid];
    if (b == K - 1 && tid == 0) rowptr[node0 + BK] = s1;
    // pull: 32 node-slots x 16 dims, 2 passes
    int d = tid & 15, slot = tid >> 4;
    #pragma unroll
    for (int pass = 0; pass < 2; ++pass) {
        int nl = pass * 32 + slot;
        int node = node0 + nl;
        if (node < n) {
            int t0 = lofs[nl], t1 = lofs[nl + 1];
            float a0 = 0.f, a1 = 0.f;
            int k = t0;
            if (fits) {
                for (; k + 1 < t1; k += 2) {
                    a0 += xn[(size_t)lsrc[k] * HID + d];
                    a1 += xn[(size_t)lsrc[k + 1] * HID + d];
                }
                if (k < t1) a0 += xn[(size_t)lsrc[k] * HID + d];
            } else {
                for (; k < t1; ++k) a0 += xn[(size_t)fsrc[s0 + k] * HID + d];
            }
            float dg = fmaxf((float)(t1 - t0), 1.0f);
            float v = xs[(size_t)node * HID + d] + (a0 + a1) / dg + b1[d];
            h[(size_t)node * HID + d] = fmaxf(v, 0.f);
        }
    }
}

// ---- K5: per-bucket pull of h + fused output GEMM.
__global__ void __launch_bounds__(512)
k_agg2_out(const int* __restrict__ fsrc, const int* __restrict__ rowptr,
           const float* __restrict__ h,
           const float* __restrict__ Ws2, const float* __restrict__ Wn2,
           const float* __restrict__ b2, float* __restrict__ out, int n) {
    __shared__ int   lidx[CAP];
    __shared__ int   lofs[BK + 1];
    __shared__ float lh[BK][HID];
    __shared__ float lagg[BK][HID];
    __shared__ float lws[HID][OUT];
    __shared__ float lwn[HID][OUT];
    __shared__ float lb2v[OUT];
    int tid = threadIdx.x, b = blockIdx.x;
    int node0 = b * BK;
    int s0r = rowptr[node0];
    int s1r = rowptr[node0 + BK];
    int cnt = s1r - s0r;
    bool fits = (cnt <= CAP);
    if (tid <= BK) lofs[tid] = rowptr[node0 + tid] - s0r;
    if (fits)
        for (int i = tid; i < cnt; i += 512) lidx[i] = fsrc[s0r + i];
    for (int i = tid; i < BK * HID; i += 512) {
        int node = node0 + (i >> 4);
        lh[i >> 4][i & 15] = (node < n) ? h[(size_t)node * HID + (i & 15)] : 0.f;
    }
    for (int i = tid; i < HID * OUT; i += 512) {
        ((float*)lws)[i] = Ws2[i];
        ((float*)lwn)[i] = Wn2[i];
    }
    if (tid < OUT) lb2v[tid] = b2[tid];
    __syncthreads();
    int d = tid & 15, slot = tid >> 4;
    #pragma unroll
    for (int pass = 0; pass < 2; ++pass) {
        int nl = pass * 32 + slot;
        int t0 = lofs[nl], t1 = lofs[nl + 1];
        float a0 = 0.f, a1 = 0.f;
        int k = t0;
        if (fits) {
            for (; k + 1 < t1; k += 2) {
                a0 += h[(size_t)lidx[k] * HID + d];
                a1 += h[(size_t)lidx[k + 1] * HID + d];
            }
            if (k < t1) a0 += h[(size_t)lidx[k] * HID + d];
        } else {
            for (; k < t1; ++k) a0 += h[(size_t)fsrc[s0r + k] * HID + d];
        }
        float dg = fmaxf((float)(t1 - t0), 1.0f);
        lagg[nl][d] = (a0 + a1) / dg;
    }
    __syncthreads();
    for (int i = tid; i < BK * OUT; i += 512) {
        int nl = i >> 6, o = i & 63;
        int node = node0 + nl;
        if (node >= n) continue;
        float acm = lb2v[o];
        #pragma unroll
        for (int j = 0; j < HID; ++j)
            acm += lh[nl][j] * lws[j][o] + lagg[nl][j] * lwn[j][o];
        out[(size_t)node * OUT + o] = acm;
    }
}

extern "C" void kernel_launch(void* const* d_in, const int* in_sizes, int n_in,
                              void* d_out, int out_size, void* d_ws, size_t ws_size,
                              hipStream_t stream) {
    const float* x   = (const float*)d_in[0];
    const int*   src = (const int*)d_in[1];
    const int*   dst = (const int*)d_in[2];
    const float* Ws1 = (const float*)d_in[3];
    const float* Wn1 = (const float*)d_in[4];
    const float* b1  = (const float*)d_in[5];
    const float* Ws2 = (const float*)d_in[6];
    const float* Wn2 = (const float*)d_in[7];
    const float* b2  = (const float*)d_in[8];
    float* out = (float*)d_out;

    int n = in_sizes[0] / IN;          // 50000
    int e = in_sizes[1];               // 800000
    int K = (n + BK - 1) / BK;         // 782 buckets
    int B = (e + EPB - 1) / EPB;       // 49 partition blocks
    int T = K * B;                     // histT entries
    int nproj = (n + PB - 1) / PB;     // 782 proj blocks

    // ws: histT[T] | boff[K+1] | rowptr[K*BK+1] | bedge[e] | fsrc[e] | xs | xn | h
    int* histT  = (int*)d_ws;
    int* boff   = histT + T;
    int* rowptr = boff + (K + 1);
    unsigned* bedge = (unsigned*)(rowptr + ((size_t)K * BK + 1));
    int* fsrc = (int*)(bedge + e);
    float* xs = (float*)(fsrc + e);
    float* xn = xs + (size_t)n * HID;
    float* h  = xn + (size_t)n * HID;

    k_proj_part1<<<nproj + B, 256, 0, stream>>>(x, Ws1, Wn1, dst, xs, xn,
                                                histT, n, e, nproj, K, B);
    k_scanAB<<<1, 1024, 0, stream>>>(histT, boff, K, B, e);
    k_part2<<<B, 1024, 0, stream>>>(src, dst, histT, boff, bedge, e, K, B);

    k_agg1<<<K, 512, 0, stream>>>(bedge, boff, xs, xn, b1, h, fsrc, rowptr, n, K);
    k_agg2_out<<<K, 512, 0, stream>>>(fsrc, rowptr, h, Ws2, Wn2, b2, out, n);
}

// Round 10
// 94.933 us; speedup vs baseline: 1.1754x; 1.1754x over previous
//
#include <hip/hip_runtime.h>

#define IN   128
#define HID  16
#define OUT  64
#define BK   64        // nodes per bucket (bucket = dst >> 6)
#define EPB  16384     // edges per partition block
#define CAP  2048      // LDS staging capacity per bucket (mean ~1024)

// ---- K1: xs[i] = x[i]@Ws1 ; xn[i] = x[i]@Wn1  (R7-proven: 8 nodes/block)
__global__ void k_proj(const float* __restrict__ x,
                       const float* __restrict__ Ws,
                       const float* __restrict__ Wn,
                       float* __restrict__ xs,
                       float* __restrict__ xn, int n) {
    __shared__ float lw[IN][32];
    __shared__ float lx[8][IN];
    int tid = threadIdx.x;  // 256
    for (int i = tid; i < IN * 32; i += 256) {
        int k = i >> 5, j = i & 31;
        lw[k][j] = (j < HID) ? Ws[k * HID + j] : Wn[k * HID + (j - 16)];
    }
    int node0 = blockIdx.x * 8;
    for (int i = tid; i < 8 * IN; i += 256) {
        int r = i >> 7, c = i & 127;
        int node = node0 + r;
        lx[r][c] = (node < n) ? x[(size_t)node * IN + c] : 0.f;
    }
    __syncthreads();
    int r = tid >> 5, j = tid & 31;
    int node = node0 + r;
    if (node >= n) return;
    float acc = 0.f;
    #pragma unroll
    for (int k = 0; k < IN; ++k) acc += lx[r][k] * lw[k][j];
    if (j < HID) xs[(size_t)node * HID + j] = acc;
    else         xn[(size_t)node * HID + (j - 16)] = acc;
}

// ---- K2: per-block LDS histogram of dst>>6 -> histT[bucket*B + blk]
__global__ void __launch_bounds__(1024)
k_part1(const int* __restrict__ dst, int* __restrict__ histT,
        int e, int K, int B) {
    __shared__ int lh[1024];
    int tid = threadIdx.x, blk = blockIdx.x;
    for (int i = tid; i < K; i += 1024) lh[i] = 0;
    __syncthreads();
    const int4* d4 = (const int4*)dst;
    #pragma unroll
    for (int it = 0; it < EPB / 4096; ++it) {
        int i4 = blk * (EPB / 4) + it * 1024 + tid;
        int elem = i4 * 4;
        if (elem + 3 < e) {
            int4 v = d4[i4];
            atomicAdd(&lh[v.x >> 6], 1);
            atomicAdd(&lh[v.y >> 6], 1);
            atomicAdd(&lh[v.z >> 6], 1);
            atomicAdd(&lh[v.w >> 6], 1);
        } else {
            for (int j = elem; j < e && j < elem + 4; ++j)
                atomicAdd(&lh[dst[j] >> 6], 1);
        }
    }
    __syncthreads();
    for (int b = tid; b < K; b += 1024) histT[b * B + blk] = lh[b];
}

// ---- K3: one WAVE per bucket: shfl-scan the B (<=64) chunk counts in place.
__global__ void k_rowscan(int* __restrict__ histT, int* __restrict__ btot,
                          int K, int B) {
    int wid = (blockIdx.x * blockDim.x + threadIdx.x) >> 6;
    int lane = threadIdx.x & 63;
    if (wid >= K) return;
    size_t base = (size_t)wid * B;
    int v = (lane < B) ? histT[base + lane] : 0;
    int incl = v;
    #pragma unroll
    for (int off = 1; off < 64; off <<= 1) {
        int t = __shfl_up(incl, off);
        if (lane >= off) incl += t;
    }
    if (lane < B) histT[base + lane] = incl - v;   // exclusive within row
    int tot = __shfl(incl, B - 1);
    if (lane == 0) btot[wid] = tot;
}

// ---- K4: exclusive scan of K bucket totals (K <= 1024), LDS only
__global__ void __launch_bounds__(1024)
k_scanB(const int* __restrict__ btot, int* __restrict__ boff, int K, int e) {
    __shared__ int sm[1024];
    int tid = threadIdx.x;
    int v = (tid < K) ? btot[tid] : 0;
    sm[tid] = v;
    __syncthreads();
    for (int off = 1; off < 1024; off <<= 1) {
        int t = (tid >= off) ? sm[tid - off] : 0;
        __syncthreads();
        sm[tid] += t;
        __syncthreads();
    }
    if (tid < K) boff[tid] = sm[tid] - v;
    if (tid == 0) boff[K] = e;
}

// ---- K5: scatter; base = boff[b] + scanned histT (two direct loads, no walk)
__global__ void __launch_bounds__(1024)
k_part2(const int* __restrict__ src, const int* __restrict__ dst,
        const int* __restrict__ histT, const int* __restrict__ boff,
        unsigned* __restrict__ bedge, int e, int K, int B) {
    __shared__ int lbase[1024];
    int tid = threadIdx.x, blk = blockIdx.x;
    for (int b = tid; b < K; b += 1024)
        lbase[b] = boff[b] + histT[(size_t)b * B + blk];
    __syncthreads();
    const int4* s4 = (const int4*)src;
    const int4* d4 = (const int4*)dst;
    #pragma unroll
    for (int it = 0; it < EPB / 4096; ++it) {
        int i4 = blk * (EPB / 4) + it * 1024 + tid;
        int elem = i4 * 4;
        if (elem + 3 < e) {
            int4 sv = s4[i4];
            int4 dv = d4[i4];
            int p0 = atomicAdd(&lbase[dv.x >> 6], 1);
            int p1 = atomicAdd(&lbase[dv.y >> 6], 1);
            int p2 = atomicAdd(&lbase[dv.z >> 6], 1);
            int p3 = atomicAdd(&lbase[dv.w >> 6], 1);
            bedge[p0] = ((unsigned)sv.x << 6) | (unsigned)(dv.x & 63);
            bedge[p1] = ((unsigned)sv.y << 6) | (unsigned)(dv.y & 63);
            bedge[p2] = ((unsigned)sv.z << 6) | (unsigned)(dv.z & 63);
            bedge[p3] = ((unsigned)sv.w << 6) | (unsigned)(dv.w & 63);
        } else {
            for (int j = elem; j < e && j < elem + 4; ++j) {
                int pos = atomicAdd(&lbase[dst[j] >> 6], 1);
                bedge[pos] = ((unsigned)src[j] << 6) | (unsigned)(dst[j] & 63);
            }
        }
    }
}

// ---- K6: per-bucket fine segmentation + register pull + relu finish.
//      Also emits fine CSR (fsrc, rowptr) for K7.
__global__ void __launch_bounds__(512)
k_agg1(const unsigned* __restrict__ bedge, const int* __restrict__ boff,
       const float* __restrict__ xs, const float* __restrict__ xn,
       const float* __restrict__ b1, float* __restrict__ h,
       int* __restrict__ fsrc, int* __restrict__ rowptr, int n, int K) {
    __shared__ int ltmp[CAP];
    __shared__ int lsrc[CAP];
    __shared__ int lcnt[BK];
    __shared__ int lofs[BK + 1];
    __shared__ int lcur[BK];
    int tid = threadIdx.x, b = blockIdx.x;
    int s0 = boff[b], s1 = boff[b + 1], cnt = s1 - s0;
    bool fits = (cnt <= CAP);
    if (tid < BK) lcnt[tid] = 0;
    __syncthreads();
    if (fits) {
        for (int i = tid; i < cnt; i += 512) {
            int p = (int)bedge[s0 + i];
            ltmp[i] = p;
            atomicAdd(&lcnt[p & 63], 1);
        }
    } else {
        for (int i = tid; i < cnt; i += 512)
            atomicAdd(&lcnt[(int)bedge[s0 + i] & 63], 1);
    }
    __syncthreads();
    if (tid < BK) {               // wave-level inclusive shfl scan of 64 counts
        int v = lcnt[tid];
        #pragma unroll
        for (int off = 1; off < 64; off <<= 1) {
            int t = __shfl_up(v, off);
            if (tid >= off) v += t;
        }
        lofs[tid + 1] = v;
        if (tid == 0) lofs[0] = 0;
        lcur[tid] = lofs[tid];
    }
    __syncthreads();
    if (fits) {
        for (int i = tid; i < cnt; i += 512) {
            int p = ltmp[i];
            int r = atomicAdd(&lcur[p & 63], 1);
            lsrc[r] = p >> 6;
        }
    } else {
        for (int i = tid; i < cnt; i += 512) {
            int p = (int)bedge[s0 + i];
            int r = atomicAdd(&lcur[p & 63], 1);
            fsrc[s0 + r] = p >> 6;
        }
        __threadfence_block();
    }
    __syncthreads();
    if (fits)
        for (int i = tid; i < cnt; i += 512) fsrc[s0 + i] = lsrc[i];
    int node0 = b * BK;
    if (tid < BK) rowptr[node0 + tid] = s0 + lofs[tid];
    if (b == K - 1 && tid == 0) rowptr[node0 + BK] = s1;
    // pull: 32 node-slots x 16 dims, 2 passes
    int d = tid & 15, slot = tid >> 4;
    #pragma unroll
    for (int pass = 0; pass < 2; ++pass) {
        int nl = pass * 32 + slot;
        int node = node0 + nl;
        if (node < n) {
            int t0 = lofs[nl], t1 = lofs[nl + 1];
            float a0 = 0.f, a1 = 0.f;
            int k = t0;
            if (fits) {
                for (; k + 1 < t1; k += 2) {
                    a0 += xn[(size_t)lsrc[k] * HID + d];
                    a1 += xn[(size_t)lsrc[k + 1] * HID + d];
                }
                if (k < t1) a0 += xn[(size_t)lsrc[k] * HID + d];
            } else {
                for (; k < t1; ++k) a0 += xn[(size_t)fsrc[s0 + k] * HID + d];
            }
            float dg = fmaxf((float)(t1 - t0), 1.0f);
            float v = xs[(size_t)node * HID + d] + (a0 + a1) / dg + b1[d];
            h[(size_t)node * HID + d] = fmaxf(v, 0.f);
        }
    }
}

// ---- K7: per-bucket pull of h + fused output GEMM.
__global__ void __launch_bounds__(512)
k_agg2_out(const int* __restrict__ fsrc, const int* __restrict__ rowptr,
           const float* __restrict__ h,
           const float* __restrict__ Ws2, const float* __restrict__ Wn2,
           const float* __restrict__ b2, float* __restrict__ out, int n) {
    __shared__ int   lidx[CAP];
    __shared__ int   lofs[BK + 1];
    __shared__ float lh[BK][HID];
    __shared__ float lagg[BK][HID];
    __shared__ float lws[HID][OUT];
    __shared__ float lwn[HID][OUT];
    __shared__ float lb2v[OUT];
    int tid = threadIdx.x, b = blockIdx.x;
    int node0 = b * BK;
    int s0r = rowptr[node0];
    int s1r = rowptr[node0 + BK];
    int cnt = s1r - s0r;
    bool fits = (cnt <= CAP);
    if (tid <= BK) lofs[tid] = rowptr[node0 + tid] - s0r;
    if (fits)
        for (int i = tid; i < cnt; i += 512) lidx[i] = fsrc[s0r + i];
    for (int i = tid; i < BK * HID; i += 512) {
        int node = node0 + (i >> 4);
        lh[i >> 4][i & 15] = (node < n) ? h[(size_t)node * HID + (i & 15)] : 0.f;
    }
    for (int i = tid; i < HID * OUT; i += 512) {
        ((float*)lws)[i] = Ws2[i];
        ((float*)lwn)[i] = Wn2[i];
    }
    if (tid < OUT) lb2v[tid] = b2[tid];
    __syncthreads();
    int d = tid & 15, slot = tid >> 4;
    #pragma unroll
    for (int pass = 0; pass < 2; ++pass) {
        int nl = pass * 32 + slot;
        int t0 = lofs[nl], t1 = lofs[nl + 1];
        float a0 = 0.f, a1 = 0.f;
        int k = t0;
        if (fits) {
            for (; k + 1 < t1; k += 2) {
                a0 += h[(size_t)lidx[k] * HID + d];
                a1 += h[(size_t)lidx[k + 1] * HID + d];
            }
            if (k < t1) a0 += h[(size_t)lidx[k] * HID + d];
        } else {
            for (; k < t1; ++k) a0 += h[(size_t)fsrc[s0r + k] * HID + d];
        }
        float dg = fmaxf((float)(t1 - t0), 1.0f);
        lagg[nl][d] = (a0 + a1) / dg;
    }
    __syncthreads();
    for (int i = tid; i < BK * OUT; i += 512) {
        int nl = i >> 6, o = i & 63;
        int node = node0 + nl;
        if (node >= n) continue;
        float acm = lb2v[o];
        #pragma unroll
        for (int j = 0; j < HID; ++j)
            acm += lh[nl][j] * lws[j][o] + lagg[nl][j] * lwn[j][o];
        out[(size_t)node * OUT + o] = acm;
    }
}

extern "C" void kernel_launch(void* const* d_in, const int* in_sizes, int n_in,
                              void* d_out, int out_size, void* d_ws, size_t ws_size,
                              hipStream_t stream) {
    const float* x   = (const float*)d_in[0];
    const int*   src = (const int*)d_in[1];
    const int*   dst = (const int*)d_in[2];
    const float* Ws1 = (const float*)d_in[3];
    const float* Wn1 = (const float*)d_in[4];
    const float* b1  = (const float*)d_in[5];
    const float* Ws2 = (const float*)d_in[6];
    const float* Wn2 = (const float*)d_in[7];
    const float* b2  = (const float*)d_in[8];
    float* out = (float*)d_out;

    int n = in_sizes[0] / IN;          // 50000
    int e = in_sizes[1];               // 800000
    int K = (n + BK - 1) / BK;         // 782 buckets
    int B = (e + EPB - 1) / EPB;       // 49 partition blocks (<= 64 for rowscan)
    int T = K * B;

    // ws: histT[T] | btot[K] | boff[K+1] | rowptr[K*BK+1] | bedge[e] | fsrc[e] | xs | xn | h
    int* histT  = (int*)d_ws;
    int* btot   = histT + T;
    int* boff   = btot + K;
    int* rowptr = boff + (K + 1);
    unsigned* bedge = (unsigned*)(rowptr + ((size_t)K * BK + 1));
    int* fsrc = (int*)(bedge + e);
    float* xs = (float*)(fsrc + e);
    float* xn = xs + (size_t)n * HID;
    float* h  = xn + (size_t)n * HID;

    k_proj<<<(n + 7) / 8, 256, 0, stream>>>(x, Ws1, Wn1, xs, xn, n);
    k_part1<<<B, 1024, 0, stream>>>(dst, histT, e, K, B);
    k_rowscan<<<(K * 64 + 255) / 256, 256, 0, stream>>>(histT, btot, K, B);
    k_scanB<<<1, 1024, 0, stream>>>(btot, boff, K, e);
    k_part2<<<B, 1024, 0, stream>>>(src, dst, histT, boff, bedge, e, K, B);

    k_agg1<<<K, 512, 0, stream>>>(bedge, boff, xs, xn, b1, h, fsrc, rowptr, n, K);
    k_agg2_out<<<K, 512, 0, stream>>>(fsrc, rowptr, h, Ws2, Wn2, b2, out, n);
}

// Round 11
// 88.542 us; speedup vs baseline: 1.2602x; 1.0722x over previous
//
#include <hip/hip_runtime.h>

#define IN   128
#define HID  16
#define OUT  64
#define BK   64        // nodes per bucket (bucket = dst >> 6)
#define EPB  4096      // edges per partition block (B=196 blocks -> full CU coverage)
#define CAP  2048      // LDS staging capacity per bucket (mean ~1024)

// ---- K1: xs[i] = x[i]@Ws1 ; xn[i] = x[i]@Wn1  (R7-proven: 8 nodes/block)
__global__ void k_proj(const float* __restrict__ x,
                       const float* __restrict__ Ws,
                       const float* __restrict__ Wn,
                       float* __restrict__ xs,
                       float* __restrict__ xn, int n) {
    __shared__ float lw[IN][32];
    __shared__ float lx[8][IN];
    int tid = threadIdx.x;  // 256
    for (int i = tid; i < IN * 32; i += 256) {
        int k = i >> 5, j = i & 31;
        lw[k][j] = (j < HID) ? Ws[k * HID + j] : Wn[k * HID + (j - 16)];
    }
    int node0 = blockIdx.x * 8;
    for (int i = tid; i < 8 * IN; i += 256) {
        int r = i >> 7, c = i & 127;
        int node = node0 + r;
        lx[r][c] = (node < n) ? x[(size_t)node * IN + c] : 0.f;
    }
    __syncthreads();
    int r = tid >> 5, j = tid & 31;
    int node = node0 + r;
    if (node >= n) return;
    float acc = 0.f;
    #pragma unroll
    for (int k = 0; k < IN; ++k) acc += lx[r][k] * lw[k][j];
    if (j < HID) xs[(size_t)node * HID + j] = acc;
    else         xn[(size_t)node * HID + (j - 16)] = acc;
}

// ---- K2: per-block LDS histogram of dst>>6 -> histT[blk*K + bucket] (coalesced)
__global__ void __launch_bounds__(512)
k_part1(const int* __restrict__ dst, int* __restrict__ histT,
        int e, int K, int B) {
    __shared__ int lh[1024];
    int tid = threadIdx.x, blk = blockIdx.x;
    for (int i = tid; i < K; i += 512) lh[i] = 0;
    __syncthreads();
    const int4* d4 = (const int4*)dst;
    #pragma unroll
    for (int it = 0; it < EPB / 2048; ++it) {     // 512 thr x 4 edges x 2
        int i4 = blk * (EPB / 4) + it * 512 + tid;
        int elem = i4 * 4;
        if (elem + 3 < e) {
            int4 v = d4[i4];
            atomicAdd(&lh[v.x >> 6], 1);
            atomicAdd(&lh[v.y >> 6], 1);
            atomicAdd(&lh[v.z >> 6], 1);
            atomicAdd(&lh[v.w >> 6], 1);
        } else {
            for (int j = elem; j < e && j < elem + 4; ++j)
                atomicAdd(&lh[dst[j] >> 6], 1);
        }
    }
    __syncthreads();
    for (int b = tid; b < K; b += 512) histT[(size_t)blk * K + b] = lh[b];
}

// ---- K3: one BLOCK per bucket: LDS-scan the B (<=256) chunk counts in place.
__global__ void __launch_bounds__(256)
k_rowscan(int* __restrict__ histT, int* __restrict__ btot, int K, int B) {
    __shared__ int sm[256];
    int b = blockIdx.x;
    int t = threadIdx.x;
    int v = (t < B) ? histT[(size_t)t * K + b] : 0;
    sm[t] = v;
    __syncthreads();
    for (int off = 1; off < 256; off <<= 1) {
        int u = (t >= off) ? sm[t - off] : 0;
        __syncthreads();
        sm[t] += u;
        __syncthreads();
    }
    if (t < B) histT[(size_t)t * K + b] = sm[t] - v;   // exclusive within row
    if (t == 255) btot[b] = sm[255];
}

// ---- K4: exclusive scan of K bucket totals (K <= 1024), LDS only
__global__ void __launch_bounds__(1024)
k_scanB(const int* __restrict__ btot, int* __restrict__ boff, int K, int e) {
    __shared__ int sm[1024];
    int tid = threadIdx.x;
    int v = (tid < K) ? btot[tid] : 0;
    sm[tid] = v;
    __syncthreads();
    for (int off = 1; off < 1024; off <<= 1) {
        int t = (tid >= off) ? sm[tid - off] : 0;
        __syncthreads();
        sm[tid] += t;
        __syncthreads();
    }
    if (tid < K) boff[tid] = sm[tid] - v;
    if (tid == 0) boff[K] = e;
}

// ---- K5: scatter; base = boff[b] + histT[blk*K+b] (two coalesced loads, no walk)
__global__ void __launch_bounds__(512)
k_part2(const int* __restrict__ src, const int* __restrict__ dst,
        const int* __restrict__ histT, const int* __restrict__ boff,
        unsigned* __restrict__ bedge, int e, int K, int B) {
    __shared__ int lbase[1024];
    int tid = threadIdx.x, blk = blockIdx.x;
    for (int b = tid; b < K; b += 512)
        lbase[b] = boff[b] + histT[(size_t)blk * K + b];
    __syncthreads();
    const int4* s4 = (const int4*)src;
    const int4* d4 = (const int4*)dst;
    #pragma unroll
    for (int it = 0; it < EPB / 2048; ++it) {
        int i4 = blk * (EPB / 4) + it * 512 + tid;
        int elem = i4 * 4;
        if (elem + 3 < e) {
            int4 sv = s4[i4];
            int4 dv = d4[i4];
            int p0 = atomicAdd(&lbase[dv.x >> 6], 1);
            int p1 = atomicAdd(&lbase[dv.y >> 6], 1);
            int p2 = atomicAdd(&lbase[dv.z >> 6], 1);
            int p3 = atomicAdd(&lbase[dv.w >> 6], 1);
            bedge[p0] = ((unsigned)sv.x << 6) | (unsigned)(dv.x & 63);
            bedge[p1] = ((unsigned)sv.y << 6) | (unsigned)(dv.y & 63);
            bedge[p2] = ((unsigned)sv.z << 6) | (unsigned)(dv.z & 63);
            bedge[p3] = ((unsigned)sv.w << 6) | (unsigned)(dv.w & 63);
        } else {
            for (int j = elem; j < e && j < elem + 4; ++j) {
                int pos = atomicAdd(&lbase[dst[j] >> 6], 1);
                bedge[pos] = ((unsigned)src[j] << 6) | (unsigned)(dst[j] & 63);
            }
        }
    }
}

// ---- K6: per-bucket fine segmentation + register pull + relu finish.
//      Also emits fine CSR (fsrc, rowptr) for K7.
__global__ void __launch_bounds__(512)
k_agg1(const unsigned* __restrict__ bedge, const int* __restrict__ boff,
       const float* __restrict__ xs, const float* __restrict__ xn,
       const float* __restrict__ b1, float* __restrict__ h,
       int* __restrict__ fsrc, int* __restrict__ rowptr, int n, int K) {
    __shared__ int ltmp[CAP];
    __shared__ int lsrc[CAP];
    __shared__ int lcnt[BK];
    __shared__ int lofs[BK + 1];
    __shared__ int lcur[BK];
    int tid = threadIdx.x, b = blockIdx.x;
    int s0 = boff[b], s1 = boff[b + 1], cnt = s1 - s0;
    bool fits = (cnt <= CAP);
    if (tid < BK) lcnt[tid] = 0;
    __syncthreads();
    if (fits) {
        for (int i = tid; i < cnt; i += 512) {
            int p = (int)bedge[s0 + i];
            ltmp[i] = p;
            atomicAdd(&lcnt[p & 63], 1);
        }
    } else {
        for (int i = tid; i < cnt; i += 512)
            atomicAdd(&lcnt[(int)bedge[s0 + i] & 63], 1);
    }
    __syncthreads();
    if (tid < BK) {               // wave-level inclusive shfl scan of 64 counts
        int v = lcnt[tid];
        #pragma unroll
        for (int off = 1; off < 64; off <<= 1) {
            int t = __shfl_up(v, off);
            if (tid >= off) v += t;
        }
        lofs[tid + 1] = v;
        if (tid == 0) lofs[0] = 0;
        lcur[tid] = lofs[tid];
    }
    __syncthreads();
    if (fits) {
        for (int i = tid; i < cnt; i += 512) {
            int p = ltmp[i];
            int r = atomicAdd(&lcur[p & 63], 1);
            lsrc[r] = p >> 6;
        }
    } else {
        for (int i = tid; i < cnt; i += 512) {
            int p = (int)bedge[s0 + i];
            int r = atomicAdd(&lcur[p & 63], 1);
            fsrc[s0 + r] = p >> 6;
        }
        __threadfence_block();
    }
    __syncthreads();
    if (fits)
        for (int i = tid; i < cnt; i += 512) fsrc[s0 + i] = lsrc[i];
    int node0 = b * BK;
    if (tid < BK) rowptr[node0 + tid] = s0 + lofs[tid];
    if (b == K - 1 && tid == 0) rowptr[node0 + BK] = s1;
    // pull: 32 node-slots x 16 dims, 2 passes
    int d = tid & 15, slot = tid >> 4;
    #pragma unroll
    for (int pass = 0; pass < 2; ++pass) {
        int nl = pass * 32 + slot;
        int node = node0 + nl;
        if (node < n) {
            int t0 = lofs[nl], t1 = lofs[nl + 1];
            float a0 = 0.f, a1 = 0.f;
            int k = t0;
            if (fits) {
                for (; k + 1 < t1; k += 2) {
                    a0 += xn[(size_t)lsrc[k] * HID + d];
                    a1 += xn[(size_t)lsrc[k + 1] * HID + d];
                }
                if (k < t1) a0 += xn[(size_t)lsrc[k] * HID + d];
            } else {
                for (; k < t1; ++k) a0 += xn[(size_t)fsrc[s0 + k] * HID + d];
            }
            float dg = fmaxf((float)(t1 - t0), 1.0f);
            float v = xs[(size_t)node * HID + d] + (a0 + a1) / dg + b1[d];
            h[(size_t)node * HID + d] = fmaxf(v, 0.f);
        }
    }
}

// ---- K7: per-bucket pull of h + fused output GEMM.
__global__ void __launch_bounds__(512)
k_agg2_out(const int* __restrict__ fsrc, const int* __restrict__ rowptr,
           const float* __restrict__ h,
           const float* __restrict__ Ws2, const float* __restrict__ Wn2,
           const float* __restrict__ b2, float* __restrict__ out, int n) {
    __shared__ int   lidx[CAP];
    __shared__ int   lofs[BK + 1];
    __shared__ float lh[BK][HID];
    __shared__ float lagg[BK][HID];
    __shared__ float lws[HID][OUT];
    __shared__ float lwn[HID][OUT];
    __shared__ float lb2v[OUT];
    int tid = threadIdx.x, b = blockIdx.x;
    int node0 = b * BK;
    int s0r = rowptr[node0];
    int s1r = rowptr[node0 + BK];
    int cnt = s1r - s0r;
    bool fits = (cnt <= CAP);
    if (tid <= BK) lofs[tid] = rowptr[node0 + tid] - s0r;
    if (fits)
        for (int i = tid; i < cnt; i += 512) lidx[i] = fsrc[s0r + i];
    for (int i = tid; i < BK * HID; i += 512) {
        int node = node0 + (i >> 4);
        lh[i >> 4][i & 15] = (node < n) ? h[(size_t)node * HID + (i & 15)] : 0.f;
    }
    for (int i = tid; i < HID * OUT; i += 512) {
        ((float*)lws)[i] = Ws2[i];
        ((float*)lwn)[i] = Wn2[i];
    }
    if (tid < OUT) lb2v[tid] = b2[tid];
    __syncthreads();
    int d = tid & 15, slot = tid >> 4;
    #pragma unroll
    for (int pass = 0; pass < 2; ++pass) {
        int nl = pass * 32 + slot;
        int t0 = lofs[nl], t1 = lofs[nl + 1];
        float a0 = 0.f, a1 = 0.f;
        int k = t0;
        if (fits) {
            for (; k + 1 < t1; k += 2) {
                a0 += h[(size_t)lidx[k] * HID + d];
                a1 += h[(size_t)lidx[k + 1] * HID + d];
            }
            if (k < t1) a0 += h[(size_t)lidx[k] * HID + d];
        } else {
            for (; k < t1; ++k) a0 += h[(size_t)fsrc[s0r + k] * HID + d];
        }
        float dg = fmaxf((float)(t1 - t0), 1.0f);
        lagg[nl][d] = (a0 + a1) / dg;
    }
    __syncthreads();
    for (int i = tid; i < BK * OUT; i += 512) {
        int nl = i >> 6, o = i & 63;
        int node = node0 + nl;
        if (node >= n) continue;
        float acm = lb2v[o];
        #pragma unroll
        for (int j = 0; j < HID; ++j)
            acm += lh[nl][j] * lws[j][o] + lagg[nl][j] * lwn[j][o];
        out[(size_t)node * OUT + o] = acm;
    }
}

extern "C" void kernel_launch(void* const* d_in, const int* in_sizes, int n_in,
                              void* d_out, int out_size, void* d_ws, size_t ws_size,
                              hipStream_t stream) {
    const float* x   = (const float*)d_in[0];
    const int*   src = (const int*)d_in[1];
    const int*   dst = (const int*)d_in[2];
    const float* Ws1 = (const float*)d_in[3];
    const float* Wn1 = (const float*)d_in[4];
    const float* b1  = (const float*)d_in[5];
    const float* Ws2 = (const float*)d_in[6];
    const float* Wn2 = (const float*)d_in[7];
    const float* b2  = (const float*)d_in[8];
    float* out = (float*)d_out;

    int n = in_sizes[0] / IN;          // 50000
    int e = in_sizes[1];               // 800000
    int K = (n + BK - 1) / BK;         // 782 buckets
    int B = (e + EPB - 1) / EPB;       // 196 partition blocks (<=256 for rowscan)
    int T = K * B;

    // ws: histT[T] | btot[K] | boff[K+1] | rowptr[K*BK+1] | bedge[e] | fsrc[e] | xs | xn | h
    int* histT  = (int*)d_ws;
    int* btot   = histT + T;
    int* boff   = btot + K;
    int* rowptr = boff + (K + 1);
    unsigned* bedge = (unsigned*)(rowptr + ((size_t)K * BK + 1));
    int* fsrc = (int*)(bedge + e);
    float* xs = (float*)(fsrc + e);
    float* xn = xs + (size_t)n * HID;
    float* h  = xn + (size_t)n * HID;

    k_proj<<<(n + 7) / 8, 256, 0, stream>>>(x, Ws1, Wn1, xs, xn, n);
    k_part1<<<B, 512, 0, stream>>>(dst, histT, e, K, B);
    k_rowscan<<<K, 256, 0, stream>>>(histT, btot, K, B);
    k_scanB<<<1, 1024, 0, stream>>>(btot, boff, K, e);
    k_part2<<<B, 512, 0, stream>>>(src, dst, histT, boff, bedge, e, K, B);

    k_agg1<<<K, 512, 0, stream>>>(bedge, boff, xs, xn, b1, h, fsrc, rowptr, n, K);
    k_agg2_out<<<K, 512, 0, stream>>>(fsrc, rowptr, h, Ws2, Wn2, b2, out, n);
}

// Round 12
// 84.042 us; speedup vs baseline: 1.3277x; 1.0536x over previous
//
#include <hip/hip_runtime.h>

#define IN   128
#define HID  16
#define OUT  64
#define BK   64        // nodes per bucket (bucket = dst >> 6)
#define EPB  4096      // edges per partition block (B=196 blocks)
#define CAP  2048      // LDS staging capacity per bucket (mean ~1024)

// ---- K1: xs[i] = x[i]@Ws1 ; xn[i] = x[i]@Wn1
// R12: transposed padded weights in LDS -> ds_read_b128 path (4x fewer LDS insts).
__global__ void k_proj(const float* __restrict__ x,
                       const float* __restrict__ Ws,
                       const float* __restrict__ Wn,
                       float* __restrict__ xs,
                       float* __restrict__ xn, int n) {
    __shared__ float lwT[32][132];   // [j][k], 132 = 16B-aligned pad, 4-dword bank skew
    __shared__ float lx[8][IN];
    int tid = threadIdx.x;  // 256
    for (int i = tid; i < IN * 32; i += 256) {
        int k = i >> 5, j = i & 31;
        lwT[j][k] = (j < HID) ? Ws[k * HID + j] : Wn[k * HID + (j - 16)];
    }
    int node0 = blockIdx.x * 8;
    const float4* x4 = (const float4*)x;
    float4* lx4 = (float4*)lx;       // [8][32] float4
    {
        int r = tid >> 5, c4 = tid & 31;      // exactly 256 float4: one pass
        int node = node0 + r;
        lx4[tid] = (node < n) ? x4[(size_t)node * 32 + c4]
                              : make_float4(0.f, 0.f, 0.f, 0.f);
    }
    __syncthreads();
    int r = tid >> 5, j = tid & 31;
    int node = node0 + r;
    if (node >= n) return;
    const float4* lxr = (const float4*)lx[r];
    float acc = 0.f;
    #pragma unroll 4
    for (int k4 = 0; k4 < 32; ++k4) {
        float4 xv = lxr[k4];
        float4 wv = *(const float4*)&lwT[j][k4 * 4];
        acc += xv.x * wv.x + xv.y * wv.y + xv.z * wv.z + xv.w * wv.w;
    }
    if (j < HID) xs[(size_t)node * HID + j] = acc;
    else         xn[(size_t)node * HID + (j - 16)] = acc;
}

// ---- K2: per-block LDS histogram of dst>>6 -> histT[blk*K + bucket] (coalesced)
__global__ void __launch_bounds__(512)
k_part1(const int* __restrict__ dst, int* __restrict__ histT,
        int e, int K, int B) {
    __shared__ int lh[1024];
    int tid = threadIdx.x, blk = blockIdx.x;
    for (int i = tid; i < K; i += 512) lh[i] = 0;
    __syncthreads();
    const int4* d4 = (const int4*)dst;
    #pragma unroll
    for (int it = 0; it < EPB / 2048; ++it) {     // 512 thr x 4 edges x 2
        int i4 = blk * (EPB / 4) + it * 512 + tid;
        int elem = i4 * 4;
        if (elem + 3 < e) {
            int4 v = d4[i4];
            atomicAdd(&lh[v.x >> 6], 1);
            atomicAdd(&lh[v.y >> 6], 1);
            atomicAdd(&lh[v.z >> 6], 1);
            atomicAdd(&lh[v.w >> 6], 1);
        } else {
            for (int j = elem; j < e && j < elem + 4; ++j)
                atomicAdd(&lh[dst[j] >> 6], 1);
        }
    }
    __syncthreads();
    for (int b = tid; b < K; b += 512) histT[(size_t)blk * K + b] = lh[b];
}

// ---- K3: one BLOCK per bucket: LDS-scan the B (<=256) chunk counts in place.
__global__ void __launch_bounds__(256)
k_rowscan(int* __restrict__ histT, int* __restrict__ btot, int K, int B) {
    __shared__ int sm[256];
    int b = blockIdx.x;
    int t = threadIdx.x;
    int v = (t < B) ? histT[(size_t)t * K + b] : 0;
    sm[t] = v;
    __syncthreads();
    for (int off = 1; off < 256; off <<= 1) {
        int u = (t >= off) ? sm[t - off] : 0;
        __syncthreads();
        sm[t] += u;
        __syncthreads();
    }
    if (t < B) histT[(size_t)t * K + b] = sm[t] - v;   // exclusive within row
    if (t == 255) btot[b] = sm[255];
}

// ---- K4: exclusive scan of K bucket totals (K <= 1024), LDS only
__global__ void __launch_bounds__(1024)
k_scanB(const int* __restrict__ btot, int* __restrict__ boff, int K, int e) {
    __shared__ int sm[1024];
    int tid = threadIdx.x;
    int v = (tid < K) ? btot[tid] : 0;
    sm[tid] = v;
    __syncthreads();
    for (int off = 1; off < 1024; off <<= 1) {
        int t = (tid >= off) ? sm[tid - off] : 0;
        __syncthreads();
        sm[tid] += t;
        __syncthreads();
    }
    if (tid < K) boff[tid] = sm[tid] - v;
    if (tid == 0) boff[K] = e;
}

// ---- K5: scatter; base = boff[b] + histT[blk*K+b] (two coalesced loads, no walk)
__global__ void __launch_bounds__(512)
k_part2(const int* __restrict__ src, const int* __restrict__ dst,
        const int* __restrict__ histT, const int* __restrict__ boff,
        unsigned* __restrict__ bedge, int e, int K, int B) {
    __shared__ int lbase[1024];
    int tid = threadIdx.x, blk = blockIdx.x;
    for (int b = tid; b < K; b += 512)
        lbase[b] = boff[b] + histT[(size_t)blk * K + b];
    __syncthreads();
    const int4* s4 = (const int4*)src;
    const int4* d4 = (const int4*)dst;
    #pragma unroll
    for (int it = 0; it < EPB / 2048; ++it) {
        int i4 = blk * (EPB / 4) + it * 512 + tid;
        int elem = i4 * 4;
        if (elem + 3 < e) {
            int4 sv = s4[i4];
            int4 dv = d4[i4];
            int p0 = atomicAdd(&lbase[dv.x >> 6], 1);
            int p1 = atomicAdd(&lbase[dv.y >> 6], 1);
            int p2 = atomicAdd(&lbase[dv.z >> 6], 1);
            int p3 = atomicAdd(&lbase[dv.w >> 6], 1);
            bedge[p0] = ((unsigned)sv.x << 6) | (unsigned)(dv.x & 63);
            bedge[p1] = ((unsigned)sv.y << 6) | (unsigned)(dv.y & 63);
            bedge[p2] = ((unsigned)sv.z << 6) | (unsigned)(dv.z & 63);
            bedge[p3] = ((unsigned)sv.w << 6) | (unsigned)(dv.w & 63);
        } else {
            for (int j = elem; j < e && j < elem + 4; ++j) {
                int pos = atomicAdd(&lbase[dst[j] >> 6], 1);
                bedge[pos] = ((unsigned)src[j] << 6) | (unsigned)(dst[j] & 63);
            }
        }
    }
}

// ---- K6: per-bucket fine segmentation + register pull + relu finish.
//      Also emits fine CSR (fsrc, rowptr) for K7.
__global__ void __launch_bounds__(512)
k_agg1(const unsigned* __restrict__ bedge, const int* __restrict__ boff,
       const float* __restrict__ xs, const float* __restrict__ xn,
       const float* __restrict__ b1, float* __restrict__ h,
       int* __restrict__ fsrc, int* __restrict__ rowptr, int n, int K) {
    __shared__ int ltmp[CAP];
    __shared__ int lsrc[CAP];
    __shared__ int lcnt[BK];
    __shared__ int lofs[BK + 1];
    __shared__ int lcur[BK];
    int tid = threadIdx.x, b = blockIdx.x;
    int s0 = boff[b], s1 = boff[b + 1], cnt = s1 - s0;
    bool fits = (cnt <= CAP);
    if (tid < BK) lcnt[tid] = 0;
    __syncthreads();
    if (fits) {
        for (int i = tid; i < cnt; i += 512) {
            int p = (int)bedge[s0 + i];
            ltmp[i] = p;
            atomicAdd(&lcnt[p & 63], 1);
        }
    } else {
        for (int i = tid; i < cnt; i += 512)
            atomicAdd(&lcnt[(int)bedge[s0 + i] & 63], 1);
    }
    __syncthreads();
    if (tid < BK) {               // wave-level inclusive shfl scan of 64 counts
        int v = lcnt[tid];
        #pragma unroll
        for (int off = 1; off < 64; off <<= 1) {
            int t = __shfl_up(v, off);
            if (tid >= off) v += t;
        }
        lofs[tid + 1] = v;
        if (tid == 0) lofs[0] = 0;
        lcur[tid] = lofs[tid];
    }
    __syncthreads();
    if (fits) {
        for (int i = tid; i < cnt; i += 512) {
            int p = ltmp[i];
            int r = atomicAdd(&lcur[p & 63], 1);
            lsrc[r] = p >> 6;
        }
    } else {
        for (int i = tid; i < cnt; i += 512) {
            int p = (int)bedge[s0 + i];
            int r = atomicAdd(&lcur[p & 63], 1);
            fsrc[s0 + r] = p >> 6;
        }
        __threadfence_block();
    }
    __syncthreads();
    if (fits)
        for (int i = tid; i < cnt; i += 512) fsrc[s0 + i] = lsrc[i];
    int node0 = b * BK;
    if (tid < BK) rowptr[node0 + tid] = s0 + lofs[tid];
    if (b == K - 1 && tid == 0) rowptr[node0 + BK] = s1;
    // pull: 32 node-slots x 16 dims, 2 passes
    int d = tid & 15, slot = tid >> 4;
    #pragma unroll
    for (int pass = 0; pass < 2; ++pass) {
        int nl = pass * 32 + slot;
        int node = node0 + nl;
        if (node < n) {
            int t0 = lofs[nl], t1 = lofs[nl + 1];
            float a0 = 0.f, a1 = 0.f;
            int k = t0;
            if (fits) {
                for (; k + 1 < t1; k += 2) {
                    a0 += xn[(size_t)lsrc[k] * HID + d];
                    a1 += xn[(size_t)lsrc[k + 1] * HID + d];
                }
                if (k < t1) a0 += xn[(size_t)lsrc[k] * HID + d];
            } else {
                for (; k < t1; ++k) a0 += xn[(size_t)fsrc[s0 + k] * HID + d];
            }
            float dg = fmaxf((float)(t1 - t0), 1.0f);
            float v = xs[(size_t)node * HID + d] + (a0 + a1) / dg + b1[d];
            h[(size_t)node * HID + d] = fmaxf(v, 0.f);
        }
    }
}

// ---- K7: per-bucket pull of h + fused output GEMM.
__global__ void __launch_bounds__(512)
k_agg2_out(const int* __restrict__ fsrc, const int* __restrict__ rowptr,
           const float* __restrict__ h,
           const float* __restrict__ Ws2, const float* __restrict__ Wn2,
           const float* __restrict__ b2, float* __restrict__ out, int n) {
    __shared__ int   lidx[CAP];
    __shared__ int   lofs[BK + 1];
    __shared__ float lh[BK][HID];
    __shared__ float lagg[BK][HID];
    __shared__ float lws[HID][OUT];
    __shared__ float lwn[HID][OUT];
    __shared__ float lb2v[OUT];
    int tid = threadIdx.x, b = blockIdx.x;
    int node0 = b * BK;
    int s0r = rowptr[node0];
    int s1r = rowptr[node0 + BK];
    int cnt = s1r - s0r;
    bool fits = (cnt <= CAP);
    if (tid <= BK) lofs[tid] = rowptr[node0 + tid] - s0r;
    if (fits)
        for (int i = tid; i < cnt; i += 512) lidx[i] = fsrc[s0r + i];
    for (int i = tid; i < BK * HID; i += 512) {
        int node = node0 + (i >> 4);
        lh[i >> 4][i & 15] = (node < n) ? h[(size_t)node * HID + (i & 15)] : 0.f;
    }
    for (int i = tid; i < HID * OUT; i += 512) {
        ((float*)lws)[i] = Ws2[i];
        ((float*)lwn)[i] = Wn2[i];
    }
    if (tid < OUT) lb2v[tid] = b2[tid];
    __syncthreads();
    int d = tid & 15, slot = tid >> 4;
    #pragma unroll
    for (int pass = 0; pass < 2; ++pass) {
        int nl = pass * 32 + slot;
        int t0 = lofs[nl], t1 = lofs[nl + 1];
        float a0 = 0.f, a1 = 0.f;
        int k = t0;
        if (fits) {
            for (; k + 1 < t1; k += 2) {
                a0 += h[(size_t)lidx[k] * HID + d];
                a1 += h[(size_t)lidx[k + 1] * HID + d];
            }
            if (k < t1) a0 += h[(size_t)lidx[k] * HID + d];
        } else {
            for (; k < t1; ++k) a0 += h[(size_t)fsrc[s0r + k] * HID + d];
        }
        float dg = fmaxf((float)(t1 - t0), 1.0f);
        lagg[nl][d] = (a0 + a1) / dg;
    }
    __syncthreads();
    for (int i = tid; i < BK * OUT; i += 512) {
        int nl = i >> 6, o = i & 63;
        int node = node0 + nl;
        if (node >= n) continue;
        float acm = lb2v[o];
        #pragma unroll
        for (int j = 0; j < HID; ++j)
            acm += lh[nl][j] * lws[j][o] + lagg[nl][j] * lwn[j][o];
        out[(size_t)node * OUT + o] = acm;
    }
}

extern "C" void kernel_launch(void* const* d_in, const int* in_sizes, int n_in,
                              void* d_out, int out_size, void* d_ws, size_t ws_size,
                              hipStream_t stream) {
    const float* x   = (const float*)d_in[0];
    const int*   src = (const int*)d_in[1];
    const int*   dst = (const int*)d_in[2];
    const float* Ws1 = (const float*)d_in[3];
    const float* Wn1 = (const float*)d_in[4];
    const float* b1  = (const float*)d_in[5];
    const float* Ws2 = (const float*)d_in[6];
    const float* Wn2 = (const float*)d_in[7];
    const float* b2  = (const float*)d_in[8];
    float* out = (float*)d_out;

    int n = in_sizes[0] / IN;          // 50000
    int e = in_sizes[1];               // 800000
    int K = (n + BK - 1) / BK;         // 782 buckets
    int B = (e + EPB - 1) / EPB;       // 196 partition blocks (<=256 for rowscan)
    int T = K * B;

    // ws: histT[T] | btot[K] | boff[K+1] | rowptr[K*BK+1] | bedge[e] | fsrc[e] | xs | xn | h
    int* histT  = (int*)d_ws;
    int* btot   = histT + T;
    int* boff   = btot + K;
    int* rowptr = boff + (K + 1);
    unsigned* bedge = (unsigned*)(rowptr + ((size_t)K * BK + 1));
    int* fsrc = (int*)(bedge + e);
    float* xs = (float*)(fsrc + e);
    float* xn = xs + (size_t)n * HID;
    float* h  = xn + (size_t)n * HID;

    k_proj<<<(n + 7) / 8, 256, 0, stream>>>(x, Ws1, Wn1, xs, xn, n);
    k_part1<<<B, 512, 0, stream>>>(dst, histT, e, K, B);
    k_rowscan<<<K, 256, 0, stream>>>(histT, btot, K, B);
    k_scanB<<<1, 1024, 0, stream>>>(btot, boff, K, e);
    k_part2<<<B, 512, 0, stream>>>(src, dst, histT, boff, bedge, e, K, B);

    k_agg1<<<K, 512, 0, stream>>>(bedge, boff, xs, xn, b1, h, fsrc, rowptr, n, K);
    k_agg2_out<<<K, 512, 0, stream>>>(fsrc, rowptr, h, Ws2, Wn2, b2, out, n);
}

// Round 13
// 81.333 us; speedup vs baseline: 1.3719x; 1.0333x over previous
//
#include <hip/hip_runtime.h>

#define IN   128
#define HID  16
#define OUT  64
#define BK   64        // nodes per bucket (bucket = dst >> 6)
#define EPB  4096      // edges per partition block (B=196 blocks)
#define CAP  2048      // LDS staging capacity per bucket (mean ~1024)

__device__ __forceinline__ void f4add(float4& a, const float4 v) {
    a.x += v.x; a.y += v.y; a.z += v.z; a.w += v.w;
}

// ---- K1: xs[i] = x[i]@Ws1 ; xn[i] = x[i]@Wn1  (R12-proven b128 path)
__global__ void k_proj(const float* __restrict__ x,
                       const float* __restrict__ Ws,
                       const float* __restrict__ Wn,
                       float* __restrict__ xs,
                       float* __restrict__ xn, int n) {
    __shared__ float lwT[32][132];   // [j][k], pad 132: 16B-aligned, 4-dword skew
    __shared__ float lx[8][IN];
    int tid = threadIdx.x;  // 256
    for (int i = tid; i < IN * 32; i += 256) {
        int k = i >> 5, j = i & 31;
        lwT[j][k] = (j < HID) ? Ws[k * HID + j] : Wn[k * HID + (j - 16)];
    }
    int node0 = blockIdx.x * 8;
    const float4* x4 = (const float4*)x;
    float4* lx4 = (float4*)lx;       // [8][32] float4
    {
        int r = tid >> 5, c4 = tid & 31;
        int node = node0 + r;
        lx4[tid] = (node < n) ? x4[(size_t)node * 32 + c4]
                              : make_float4(0.f, 0.f, 0.f, 0.f);
    }
    __syncthreads();
    int r = tid >> 5, j = tid & 31;
    int node = node0 + r;
    if (node >= n) return;
    const float4* lxr = (const float4*)lx[r];
    float acc = 0.f;
    #pragma unroll 4
    for (int k4 = 0; k4 < 32; ++k4) {
        float4 xv = lxr[k4];
        float4 wv = *(const float4*)&lwT[j][k4 * 4];
        acc += xv.x * wv.x + xv.y * wv.y + xv.z * wv.z + xv.w * wv.w;
    }
    if (j < HID) xs[(size_t)node * HID + j] = acc;
    else         xn[(size_t)node * HID + (j - 16)] = acc;
}

// ---- K2: per-block LDS histogram of dst>>6 -> histT[blk*K + bucket]
__global__ void __launch_bounds__(512)
k_part1(const int* __restrict__ dst, int* __restrict__ histT,
        int e, int K, int B) {
    __shared__ int lh[1024];
    int tid = threadIdx.x, blk = blockIdx.x;
    for (int i = tid; i < K; i += 512) lh[i] = 0;
    __syncthreads();
    const int4* d4 = (const int4*)dst;
    #pragma unroll
    for (int it = 0; it < EPB / 2048; ++it) {
        int i4 = blk * (EPB / 4) + it * 512 + tid;
        int elem = i4 * 4;
        if (elem + 3 < e) {
            int4 v = d4[i4];
            atomicAdd(&lh[v.x >> 6], 1);
            atomicAdd(&lh[v.y >> 6], 1);
            atomicAdd(&lh[v.z >> 6], 1);
            atomicAdd(&lh[v.w >> 6], 1);
        } else {
            for (int j = elem; j < e && j < elem + 4; ++j)
                atomicAdd(&lh[dst[j] >> 6], 1);
        }
    }
    __syncthreads();
    for (int b = tid; b < K; b += 512) histT[(size_t)blk * K + b] = lh[b];
}

// ---- K3: one BLOCK per bucket: LDS-scan the B (<=256) chunk counts in place.
__global__ void __launch_bounds__(256)
k_rowscan(int* __restrict__ histT, int* __restrict__ btot, int K, int B) {
    __shared__ int sm[256];
    int b = blockIdx.x;
    int t = threadIdx.x;
    int v = (t < B) ? histT[(size_t)t * K + b] : 0;
    sm[t] = v;
    __syncthreads();
    for (int off = 1; off < 256; off <<= 1) {
        int u = (t >= off) ? sm[t - off] : 0;
        __syncthreads();
        sm[t] += u;
        __syncthreads();
    }
    if (t < B) histT[(size_t)t * K + b] = sm[t] - v;
    if (t == 255) btot[b] = sm[255];
}

// ---- K4: exclusive scan of K bucket totals (K <= 1024), LDS only
__global__ void __launch_bounds__(1024)
k_scanB(const int* __restrict__ btot, int* __restrict__ boff, int K, int e) {
    __shared__ int sm[1024];
    int tid = threadIdx.x;
    int v = (tid < K) ? btot[tid] : 0;
    sm[tid] = v;
    __syncthreads();
    for (int off = 1; off < 1024; off <<= 1) {
        int t = (tid >= off) ? sm[tid - off] : 0;
        __syncthreads();
        sm[tid] += t;
        __syncthreads();
    }
    if (tid < K) boff[tid] = sm[tid] - v;
    if (tid == 0) boff[K] = e;
}

// ---- K5: scatter; base = boff[b] + histT[blk*K+b]
__global__ void __launch_bounds__(512)
k_part2(const int* __restrict__ src, const int* __restrict__ dst,
        const int* __restrict__ histT, const int* __restrict__ boff,
        unsigned* __restrict__ bedge, int e, int K, int B) {
    __shared__ int lbase[1024];
    int tid = threadIdx.x, blk = blockIdx.x;
    for (int b = tid; b < K; b += 512)
        lbase[b] = boff[b] + histT[(size_t)blk * K + b];
    __syncthreads();
    const int4* s4 = (const int4*)src;
    const int4* d4 = (const int4*)dst;
    #pragma unroll
    for (int it = 0; it < EPB / 2048; ++it) {
        int i4 = blk * (EPB / 4) + it * 512 + tid;
        int elem = i4 * 4;
        if (elem + 3 < e) {
            int4 sv = s4[i4];
            int4 dv = d4[i4];
            int p0 = atomicAdd(&lbase[dv.x >> 6], 1);
            int p1 = atomicAdd(&lbase[dv.y >> 6], 1);
            int p2 = atomicAdd(&lbase[dv.z >> 6], 1);
            int p3 = atomicAdd(&lbase[dv.w >> 6], 1);
            bedge[p0] = ((unsigned)sv.x << 6) | (unsigned)(dv.x & 63);
            bedge[p1] = ((unsigned)sv.y << 6) | (unsigned)(dv.y & 63);
            bedge[p2] = ((unsigned)sv.z << 6) | (unsigned)(dv.z & 63);
            bedge[p3] = ((unsigned)sv.w << 6) | (unsigned)(dv.w & 63);
        } else {
            for (int j = elem; j < e && j < elem + 4; ++j) {
                int pos = atomicAdd(&lbase[dst[j] >> 6], 1);
                bedge[pos] = ((unsigned)src[j] << 6) | (unsigned)(dst[j] & 63);
            }
        }
    }
}

// ---- K6: per-bucket fine segmentation + float4 register pull + relu finish.
//      Pull threads: tid = nl*8 + half*4 + d4  (64 nodes x 2 halves x 4 float4-dims)
__global__ void __launch_bounds__(512)
k_agg1(const unsigned* __restrict__ bedge, const int* __restrict__ boff,
       const float* __restrict__ xs, const float* __restrict__ xn,
       const float* __restrict__ b1, float* __restrict__ h,
       int* __restrict__ fsrc, int* __restrict__ rowptr, int n, int K) {
    __shared__ int ltmp[CAP];
    __shared__ int lsrc[CAP];
    __shared__ int lcnt[BK];
    __shared__ int lofs[BK + 1];
    __shared__ int lcur[BK];
    int tid = threadIdx.x, b = blockIdx.x;
    int s0 = boff[b], s1 = boff[b + 1], cnt = s1 - s0;
    bool fits = (cnt <= CAP);
    if (tid < BK) lcnt[tid] = 0;
    __syncthreads();
    if (fits) {
        for (int i = tid; i < cnt; i += 512) {
            int p = (int)bedge[s0 + i];
            ltmp[i] = p;
            atomicAdd(&lcnt[p & 63], 1);
        }
    } else {
        for (int i = tid; i < cnt; i += 512)
            atomicAdd(&lcnt[(int)bedge[s0 + i] & 63], 1);
    }
    __syncthreads();
    if (tid < BK) {               // wave-level inclusive shfl scan of 64 counts
        int v = lcnt[tid];
        #pragma unroll
        for (int off = 1; off < 64; off <<= 1) {
            int t = __shfl_up(v, off);
            if (tid >= off) v += t;
        }
        lofs[tid + 1] = v;
        if (tid == 0) lofs[0] = 0;
        lcur[tid] = lofs[tid];
    }
    __syncthreads();
    if (fits) {
        for (int i = tid; i < cnt; i += 512) {
            int p = ltmp[i];
            int r = atomicAdd(&lcur[p & 63], 1);
            lsrc[r] = p >> 6;
        }
    } else {
        for (int i = tid; i < cnt; i += 512) {
            int p = (int)bedge[s0 + i];
            int r = atomicAdd(&lcur[p & 63], 1);
            fsrc[s0 + r] = p >> 6;
        }
        __threadfence_block();
    }
    __syncthreads();
    if (fits)
        for (int i = tid; i < cnt; i += 512) fsrc[s0 + i] = lsrc[i];
    int node0 = b * BK;
    if (tid < BK) rowptr[node0 + tid] = s0 + lofs[tid];
    if (b == K - 1 && tid == 0) rowptr[node0 + BK] = s1;
    // float4 pull: each thread = (node nl, half, d4); halves interleave stride-2
    int d4 = tid & 3;
    int half = (tid >> 2) & 1;
    int nl = tid >> 3;                 // 0..63
    int node = node0 + nl;
    int t0 = lofs[nl], t1 = lofs[nl + 1];
    const float4* xn4 = (const float4*)xn;
    float4 a0 = make_float4(0.f, 0.f, 0.f, 0.f);
    float4 a1 = make_float4(0.f, 0.f, 0.f, 0.f);
    int k = t0 + half;
    if (fits) {
        for (; k + 2 < t1; k += 4) {
            f4add(a0, xn4[(size_t)lsrc[k] * 4 + d4]);
            f4add(a1, xn4[(size_t)lsrc[k + 2] * 4 + d4]);
        }
        if (k < t1) f4add(a0, xn4[(size_t)lsrc[k] * 4 + d4]);
    } else {
        for (; k < t1; k += 2) f4add(a0, xn4[(size_t)fsrc[s0 + k] * 4 + d4]);
    }
    f4add(a0, a1);
    a0.x += __shfl_xor(a0.x, 4);
    a0.y += __shfl_xor(a0.y, 4);
    a0.z += __shfl_xor(a0.z, 4);
    a0.w += __shfl_xor(a0.w, 4);
    if (half == 0 && node < n) {
        float inv = 1.0f / fmaxf((float)(t1 - t0), 1.0f);
        float4 xv = ((const float4*)xs)[(size_t)node * 4 + d4];
        float4 bv = ((const float4*)b1)[d4];
        float4 hv;
        hv.x = fmaxf(xv.x + a0.x * inv + bv.x, 0.f);
        hv.y = fmaxf(xv.y + a0.y * inv + bv.y, 0.f);
        hv.z = fmaxf(xv.z + a0.z * inv + bv.z, 0.f);
        hv.w = fmaxf(xv.w + a0.w * inv + bv.w, 0.f);
        ((float4*)h)[(size_t)node * 4 + d4] = hv;
    }
}

// ---- K7: per-bucket float4 pull of h + fused output GEMM.
__global__ void __launch_bounds__(512)
k_agg2_out(const int* __restrict__ fsrc, const int* __restrict__ rowptr,
           const float* __restrict__ h,
           const float* __restrict__ Ws2, const float* __restrict__ Wn2,
           const float* __restrict__ b2, float* __restrict__ out, int n) {
    __shared__ int   lidx[CAP];
    __shared__ int   lofs[BK + 1];
    __shared__ float lh[BK][HID];
    __shared__ float lagg[BK][HID];
    __shared__ float lws[HID][OUT];
    __shared__ float lwn[HID][OUT];
    __shared__ float lb2v[OUT];
    int tid = threadIdx.x, b = blockIdx.x;
    int node0 = b * BK;
    int s0r = rowptr[node0];
    int s1r = rowptr[node0 + BK];
    int cnt = s1r - s0r;
    bool fits = (cnt <= CAP);
    if (tid <= BK) lofs[tid] = rowptr[node0 + tid] - s0r;
    if (fits)
        for (int i = tid; i < cnt; i += 512) lidx[i] = fsrc[s0r + i];
    for (int i = tid; i < BK * HID; i += 512) {
        int node = node0 + (i >> 4);
        lh[i >> 4][i & 15] = (node < n) ? h[(size_t)node * HID + (i & 15)] : 0.f;
    }
    for (int i = tid; i < HID * OUT; i += 512) {
        ((float*)lws)[i] = Ws2[i];
        ((float*)lwn)[i] = Wn2[i];
    }
    if (tid < OUT) lb2v[tid] = b2[tid];
    __syncthreads();
    // float4 pull of h
    int d4 = tid & 3;
    int half = (tid >> 2) & 1;
    int nl = tid >> 3;
    int t0 = lofs[nl], t1 = lofs[nl + 1];
    const float4* h4 = (const float4*)h;
    float4 a0 = make_float4(0.f, 0.f, 0.f, 0.f);
    float4 a1 = make_float4(0.f, 0.f, 0.f, 0.f);
    int k = t0 + half;
    if (fits) {
        for (; k + 2 < t1; k += 4) {
            f4add(a0, h4[(size_t)lidx[k] * 4 + d4]);
            f4add(a1, h4[(size_t)lidx[k + 2] * 4 + d4]);
        }
        if (k < t1) f4add(a0, h4[(size_t)lidx[k] * 4 + d4]);
    } else {
        for (; k < t1; k += 2) f4add(a0, h4[(size_t)fsrc[s0r + k] * 4 + d4]);
    }
    f4add(a0, a1);
    a0.x += __shfl_xor(a0.x, 4);
    a0.y += __shfl_xor(a0.y, 4);
    a0.z += __shfl_xor(a0.z, 4);
    a0.w += __shfl_xor(a0.w, 4);
    if (half == 0) {
        float inv = 1.0f / fmaxf((float)(t1 - t0), 1.0f);
        float4 r;
        r.x = a0.x * inv; r.y = a0.y * inv; r.z = a0.z * inv; r.w = a0.w * inv;
        *(float4*)&lagg[nl][d4 * 4] = r;
    }
    __syncthreads();
    for (int i = tid; i < BK * OUT; i += 512) {
        int nl2 = i >> 6, o = i & 63;
        int node = node0 + nl2;
        if (node >= n) continue;
        float acm = lb2v[o];
        #pragma unroll
        for (int j = 0; j < HID; ++j)
            acm += lh[nl2][j] * lws[j][o] + lagg[nl2][j] * lwn[j][o];
        out[(size_t)node * OUT + o] = acm;
    }
}

extern "C" void kernel_launch(void* const* d_in, const int* in_sizes, int n_in,
                              void* d_out, int out_size, void* d_ws, size_t ws_size,
                              hipStream_t stream) {
    const float* x   = (const float*)d_in[0];
    const int*   src = (const int*)d_in[1];
    const int*   dst = (const int*)d_in[2];
    const float* Ws1 = (const float*)d_in[3];
    const float* Wn1 = (const float*)d_in[4];
    const float* b1  = (const float*)d_in[5];
    const float* Ws2 = (const float*)d_in[6];
    const float* Wn2 = (const float*)d_in[7];
    const float* b2  = (const float*)d_in[8];
    float* out = (float*)d_out;

    int n = in_sizes[0] / IN;          // 50000
    int e = in_sizes[1];               // 800000
    int K = (n + BK - 1) / BK;         // 782 buckets
    int B = (e + EPB - 1) / EPB;       // 196 partition blocks
    int T = K * B;

    // ws: histT[T] | btot[K] | boff[K+1] | rowptr[K*BK+1] | bedge[e] | fsrc[e] | xs | xn | h
    int* histT  = (int*)d_ws;
    int* btot   = histT + T;
    int* boff   = btot + K;
    int* rowptr = boff + (K + 1);
    unsigned* bedge = (unsigned*)(rowptr + ((size_t)K * BK + 1));
    int* fsrc = (int*)(bedge + e);
    float* xs = (float*)(fsrc + e);
    float* xn = xs + (size_t)n * HID;
    float* h  = xn + (size_t)n * HID;

    k_proj<<<(n + 7) / 8, 256, 0, stream>>>(x, Ws1, Wn1, xs, xn, n);
    k_part1<<<B, 512, 0, stream>>>(dst, histT, e, K, B);
    k_rowscan<<<K, 256, 0, stream>>>(histT, btot, K, B);
    k_scanB<<<1, 1024, 0, stream>>>(btot, boff, K, e);
    k_part2<<<B, 512, 0, stream>>>(src, dst, histT, boff, bedge, e, K, B);

    k_agg1<<<K, 512, 0, stream>>>(bedge, boff, xs, xn, b1, h, fsrc, rowptr, n, K);
    k_agg2_out<<<K, 512, 0, stream>>>(fsrc, rowptr, h, Ws2, Wn2, b2, out, n);
}